// Round 14
// baseline (269.511 us; speedup 1.0000x reference)
//
#include <hip/hip_runtime.h>
#include <math.h>

#define N_NODES 8192
#define E_EDGES 262144
#define ETOT (E_EDGES + N_NODES)
#define F_IN 256
#define NH 4
#define NC 32
#define DD 128
#define NEG_SLOPE 0.2f
#define LN_EPS 1e-5f
// attention softmax in exp2 domain: fold log2(e)/sqrt(32) into Q at pack time
#define QK_SCALE (1.4426950408889634f / 5.656854249492381f)

typedef __attribute__((ext_vector_type(8))) short bf16x8;
typedef __attribute__((ext_vector_type(4))) float f32x4;

__device__ __forceinline__ float fexp2(float x) { return __builtin_amdgcn_exp2f(x); }
__device__ __forceinline__ float flog2(float x) { return __builtin_amdgcn_logf(x); }
__device__ __forceinline__ float frcp(float x)  { return __builtin_amdgcn_rcpf(x); }

__device__ __forceinline__ unsigned short f2bf(float f) {   // RTNE
    unsigned u = __float_as_uint(f);
    u += 0x7FFFu + ((u >> 16) & 1u);
    return (unsigned short)(u >> 16);
}
__device__ __forceinline__ unsigned pk2bf(float lo, float hi) {
    unsigned a = __float_as_uint(lo) + 0x8000u;
    unsigned b = __float_as_uint(hi) + 0x8000u;
    return __builtin_amdgcn_perm(b, a, 0x07060302u);
}

// ===== weight transpose/convert to bf16 + FUSED degree count =====
__global__ __launch_bounds__(256) void k_cvt(const float* __restrict__ Wgat,
                                             const float* __restrict__ Wpro,
                                             const float* __restrict__ Wq,
                                             const float* __restrict__ Wk,
                                             unsigned short* __restrict__ Wgt,
                                             unsigned short* __restrict__ Wpt,
                                             unsigned short* __restrict__ Wqt,
                                             unsigned short* __restrict__ Wkt,
                                             const int* __restrict__ adj,
                                             int* __restrict__ deg) {
    int t = blockIdx.x * 256 + threadIdx.x;
    if (t < 32768) {
        int c = t >> 8, k = t & 255;
        Wgt[t] = f2bf(Wgat[(size_t)k * 128 + c]);
    } else if (t < 49152) {
        int i = t - 32768, c = i >> 7, k = i & 127;
        Wpt[i] = f2bf(Wpro[(size_t)k * 128 + c]);
    } else if (t < 65536) {
        int i = t - 49152, h = i >> 12, r = i & 4095, c = r >> 7, k = r & 127;
        Wqt[i] = f2bf(Wq[h * 4096 + k * 32 + c]);
    } else if (t < 81920) {
        int i = t - 65536, h = i >> 12, r = i & 4095, c = r >> 7, k = r & 127;
        Wkt[i] = f2bf(Wk[h * 4096 + k * 32 + c]);
    }
    if (t < ETOT) {
        int d = (t < E_EDGES) ? adj[E_EDGES + t] : t - E_EDGES;
        atomicAdd(&deg[d], 1);
    }
}

// ===== MFMA GEMM xw = x @ Wgat, x converted to bf16 in staging, fused attcoef =====
__global__ __launch_bounds__(256) void k_gemm_att(const float* __restrict__ x,
                                                  const unsigned short* __restrict__ Wgt,
                                                  const float* __restrict__ att_src,
                                                  const float* __restrict__ att_dst,
                                                  float* __restrict__ xw,
                                                  float* __restrict__ asrc,
                                                  float* __restrict__ adst) {
    __shared__ unsigned short xs[32 * 256];   // chunk-rotated
    const int tid = threadIdx.x;
    const int w = tid >> 6, lane = tid & 63, lq = lane & 15, g = lane >> 4;
    const int n0 = blockIdx.x * 32;
#pragma unroll
    for (int m = 0; m < 4; ++m) {             // 1024 chunk-tasks
        int lin = m * 256 + tid;
        int row = lin >> 5, ch = lin & 31;
        const float* src = &x[(size_t)(n0 + row) * 256 + ch * 8];
        float4 v0 = *(const float4*)src;
        float4 v1 = *(const float4*)(src + 4);
        uint4 o;
        o.x = (unsigned)f2bf(v0.x) | ((unsigned)f2bf(v0.y) << 16);
        o.y = (unsigned)f2bf(v0.z) | ((unsigned)f2bf(v0.w) << 16);
        o.z = (unsigned)f2bf(v1.x) | ((unsigned)f2bf(v1.y) << 16);
        o.w = (unsigned)f2bf(v1.z) | ((unsigned)f2bf(v1.w) << 16);
        *(uint4*)&xs[row * 256 + ((ch + row) & 31) * 8] = o;
    }
    __syncthreads();
    f32x4 zero = {0.f, 0.f, 0.f, 0.f};
    f32x4 acc[2][2];
#pragma unroll
    for (int s = 0; s < 2; ++s) { acc[s][0] = zero; acc[s][1] = zero; }
#pragma unroll
    for (int kb = 0; kb < 8; ++kb) {
        bf16x8 af[2], bf[2];
#pragma unroll
        for (int s = 0; s < 2; ++s) {
            int row = s * 16 + lq;
            af[s] = *(const bf16x8*)&xs[row * 256 + (((kb * 4 + g) + row) & 31) * 8];
        }
#pragma unroll
        for (int c = 0; c < 2; ++c)
            bf[c] = *(const bf16x8*)(Wgt + (size_t)(w * 32 + c * 16 + lq) * 256 + kb * 32 + g * 8);
#pragma unroll
        for (int s = 0; s < 2; ++s)
#pragma unroll
            for (int c = 0; c < 2; ++c)
                acc[s][c] = __builtin_amdgcn_mfma_f32_16x16x32_bf16(af[s], bf[c], acc[s][c], 0, 0, 0);
    }
#pragma unroll
    for (int s = 0; s < 2; ++s)
#pragma unroll
        for (int c = 0; c < 2; ++c)
#pragma unroll
            for (int r = 0; r < 4; ++r)
                xw[(size_t)(n0 + s * 16 + 4 * g + r) * DD + w * 32 + c * 16 + lq] = acc[s][c][r];
    float avs0 = att_src[w * 32 + lq],      avd0 = att_dst[w * 32 + lq];
    float avs1 = att_src[w * 32 + 16 + lq], avd1 = att_dst[w * 32 + 16 + lq];
#pragma unroll
    for (int s = 0; s < 2; ++s) {
        f32x4 vs, vd;
#pragma unroll
        for (int r = 0; r < 4; ++r) {
            vs[r] = acc[s][0][r] * avs0 + acc[s][1][r] * avs1;
            vd[r] = acc[s][0][r] * avd0 + acc[s][1][r] * avd1;
        }
#pragma unroll
        for (int off = 1; off < 16; off <<= 1)
#pragma unroll
            for (int r = 0; r < 4; ++r) {
                vs[r] += __shfl_xor(vs[r], off);
                vd[r] += __shfl_xor(vd[r], off);
            }
        if (lq == 0) {
#pragma unroll
            for (int r = 0; r < 4; ++r) {
                asrc[(n0 + s * 16 + 4 * g + r) * 4 + w] = vs[r];
                adst[(n0 + s * 16 + 4 * g + r) * 4 + w] = vd[r];
            }
        }
    }
}

// ===== MFMA GEMM h = hcat @ Wpro + hbuf f32 + Htb transpose + MFMA q/k =====
__global__ __launch_bounds__(256) void k_gemm_pro(const float* __restrict__ hcat,
                                                  const unsigned short* __restrict__ Wpt,
                                                  const unsigned short* __restrict__ Wqt,
                                                  const unsigned short* __restrict__ Wkt,
                                                  float* __restrict__ hbuf,
                                                  unsigned short* __restrict__ Htb,
                                                  unsigned short* __restrict__ Qb,
                                                  unsigned short* __restrict__ Kb) {
    __shared__ unsigned short xs[32 * 128];
    __shared__ unsigned short hsd[32 * 128];
    const int tid = threadIdx.x;
    const int w = tid >> 6, lane = tid & 63, lq = lane & 15, g = lane >> 4;
    const int n0 = blockIdx.x * 32;
#pragma unroll
    for (int m = 0; m < 2; ++m) {
        int lin = m * 256 + tid;
        int row = lin >> 4, ch = lin & 15;
        const float* src = &hcat[(size_t)(n0 + row) * 128 + ch * 8];
        float4 v0 = *(const float4*)src;
        float4 v1 = *(const float4*)(src + 4);
        uint4 o;
        o.x = (unsigned)f2bf(v0.x) | ((unsigned)f2bf(v0.y) << 16);
        o.y = (unsigned)f2bf(v0.z) | ((unsigned)f2bf(v0.w) << 16);
        o.z = (unsigned)f2bf(v1.x) | ((unsigned)f2bf(v1.y) << 16);
        o.w = (unsigned)f2bf(v1.z) | ((unsigned)f2bf(v1.w) << 16);
        *(uint4*)&xs[row * 128 + ((ch + row) & 15) * 8] = o;
    }
    __syncthreads();
    f32x4 zero = {0.f, 0.f, 0.f, 0.f};
    f32x4 acc[2][2];
#pragma unroll
    for (int s = 0; s < 2; ++s) { acc[s][0] = zero; acc[s][1] = zero; }
#pragma unroll
    for (int kb = 0; kb < 4; ++kb) {
        bf16x8 af[2], bf[2];
#pragma unroll
        for (int s = 0; s < 2; ++s) {
            int row = s * 16 + lq;
            af[s] = *(const bf16x8*)&xs[row * 128 + (((kb * 4 + g) + row) & 15) * 8];
        }
#pragma unroll
        for (int c = 0; c < 2; ++c)
            bf[c] = *(const bf16x8*)(Wpt + (size_t)(w * 32 + c * 16 + lq) * 128 + kb * 32 + g * 8);
#pragma unroll
        for (int s = 0; s < 2; ++s)
#pragma unroll
            for (int c = 0; c < 2; ++c)
                acc[s][c] = __builtin_amdgcn_mfma_f32_16x16x32_bf16(af[s], bf[c], acc[s][c], 0, 0, 0);
    }
#pragma unroll
    for (int s = 0; s < 2; ++s)
#pragma unroll
        for (int c = 0; c < 2; ++c) {
            int col = w * 32 + c * 16 + lq;
#pragma unroll
            for (int r = 0; r < 4; ++r) {
                int row = s * 16 + 4 * g + r;
                hbuf[(size_t)(n0 + row) * 128 + col] = acc[s][c][r];
                hsd[row * 128 + (((col >> 3) + row) & 15) * 8 + (col & 7)] = f2bf(acc[s][c][r]);
            }
            uint2 hp;
            hp.x = pk2bf(acc[s][c][0], acc[s][c][1]);
            hp.y = pk2bf(acc[s][c][2], acc[s][c][3]);
            *(uint2*)(Htb + (size_t)col * N_NODES + n0 + s * 16 + 4 * g) = hp;
        }
    __syncthreads();
    f32x4 aq[2][2], ak[2][2];
#pragma unroll
    for (int s = 0; s < 2; ++s)
#pragma unroll
        for (int c = 0; c < 2; ++c) { aq[s][c] = zero; ak[s][c] = zero; }
#pragma unroll
    for (int kb = 0; kb < 4; ++kb) {
        bf16x8 af[2], bq[2], bk[2];
#pragma unroll
        for (int s = 0; s < 2; ++s) {
            int row = s * 16 + lq;
            af[s] = *(const bf16x8*)&hsd[row * 128 + (((kb * 4 + g) + row) & 15) * 8];
        }
#pragma unroll
        for (int c = 0; c < 2; ++c) {
            size_t widx = ((size_t)w * 32 + c * 16 + lq) * 128 + kb * 32 + g * 8;
            bq[c] = *(const bf16x8*)(Wqt + widx);
            bk[c] = *(const bf16x8*)(Wkt + widx);
        }
#pragma unroll
        for (int s = 0; s < 2; ++s)
#pragma unroll
            for (int c = 0; c < 2; ++c) {
                aq[s][c] = __builtin_amdgcn_mfma_f32_16x16x32_bf16(af[s], bq[c], aq[s][c], 0, 0, 0);
                ak[s][c] = __builtin_amdgcn_mfma_f32_16x16x32_bf16(af[s], bk[c], ak[s][c], 0, 0, 0);
            }
    }
#pragma unroll
    for (int s = 0; s < 2; ++s)
#pragma unroll
        for (int c = 0; c < 2; ++c)
#pragma unroll
            for (int r = 0; r < 4; ++r) {
                size_t nidx = (size_t)w * N_NODES + n0 + s * 16 + 4 * g + r;
                Qb[nidx * NC + c * 16 + lq] = f2bf(aq[s][c][r] * QK_SCALE);
                Kb[nidx * NC + c * 16 + lq] = f2bf(ak[s][c][r]);
            }
}

__device__ __forceinline__ void edge_sd(int e, const int* adj, int& s, int& d) {
    if (e < E_EDGES) { s = adj[e]; d = adj[E_EDGES + e]; }
    else { s = e - E_EDGES; d = s; }
}

// ===== single-block exclusive scan over deg[8192] -> rowptr, cursor =====
__global__ __launch_bounds__(1024) void k_scan(const int* __restrict__ deg,
                                               int* __restrict__ rowptr,
                                               int* __restrict__ cursor) {
    __shared__ int sm[1024];
    int t = threadIdx.x;
    int v[8], sum = 0;
#pragma unroll
    for (int j = 0; j < 8; ++j) { v[j] = deg[t * 8 + j]; sum += v[j]; }
    sm[t] = sum;
    __syncthreads();
    for (int off = 1; off < 1024; off <<= 1) {
        int x = (t >= off) ? sm[t - off] : 0;
        __syncthreads();
        sm[t] += x;
        __syncthreads();
    }
    int base = sm[t] - sum;
#pragma unroll
    for (int j = 0; j < 8; ++j) {
        rowptr[t * 8 + j] = base;
        cursor[t * 8 + j] = base;
        base += v[j];
    }
    if (t == 1023) rowptr[8192] = base;
}

// ===== fill CSR: ONE packed 16B record per edge {src, p01 bf16, p23 bf16, 0} =====
__global__ void k_fill(const int* __restrict__ adj, const float* __restrict__ asrc,
                       const float* __restrict__ adst, int* __restrict__ cursor,
                       uint4* __restrict__ rec_csr) {
    int e = blockIdx.x * blockDim.x + threadIdx.x;
    if (e >= ETOT) return;
    int s, d; edge_sd(e, adj, s, d);
    int pos = atomicAdd(&cursor[d], 1);
    float4 as4 = *(const float4*)&asrc[s * 4];
    float4 ad4 = *(const float4*)&adst[d * 4];
    const float L2E = 1.4426950408889634f;
    float v;
    float4 p;
    v = as4.x + ad4.x; v = v > 0.f ? v : NEG_SLOPE * v; p.x = fexp2(v * L2E);
    v = as4.y + ad4.y; v = v > 0.f ? v : NEG_SLOPE * v; p.y = fexp2(v * L2E);
    v = as4.z + ad4.z; v = v > 0.f ? v : NEG_SLOPE * v; p.z = fexp2(v * L2E);
    v = as4.w + ad4.w; v = v > 0.f ? v : NEG_SLOPE * v; p.w = fexp2(v * L2E);
    uint4 rec;
    rec.x = (unsigned)s;
    rec.y = pk2bf(p.x, p.y);
    rec.z = pk2bf(p.z, p.w);
    rec.w = 0u;
    rec_csr[pos] = rec;
}

__device__ __forceinline__ float rec_p(const uint4& r, int h) {
    unsigned w = (h < 2) ? r.y : r.z;
    return __uint_as_float((h & 1) ? (w & 0xFFFF0000u) : (w << 16));
}

// ===== per-node gather-aggregate: inline denominator, 4-wide unroll =====
__global__ __launch_bounds__(256) void k_aggregate(const int* __restrict__ rowptr,
                                                   const uint4* __restrict__ rec_csr,
                                                   const float* __restrict__ xw,
                                                   const float* __restrict__ bias,
                                                   float* __restrict__ hcat) {
    int n = blockIdx.x * 2 + (threadIdx.x >> 7);
    int c = threadIdx.x & 127;
    int h = c >> 5;
    int beg = rowptr[n], end = rowptr[n + 1];
    float acc0 = 0.f, acc1 = 0.f, den0 = 0.f, den1 = 0.f;
    int i = beg;
    for (; i + 4 <= end; i += 4) {
        uint4 r0 = rec_csr[i], r1 = rec_csr[i + 1];
        uint4 r2 = rec_csr[i + 2], r3 = rec_csr[i + 3];
        float p0 = rec_p(r0, h), p1 = rec_p(r1, h);
        float p2 = rec_p(r2, h), p3 = rec_p(r3, h);
        den0 += p0 + p1;
        den1 += p2 + p3;
        acc0 += p0 * xw[(size_t)r0.x * DD + c] + p1 * xw[(size_t)r1.x * DD + c];
        acc1 += p2 * xw[(size_t)r2.x * DD + c] + p3 * xw[(size_t)r3.x * DD + c];
    }
    for (; i < end; ++i) {
        uint4 r0 = rec_csr[i];
        float p0 = rec_p(r0, h);
        den0 += p0;
        acc0 += p0 * xw[(size_t)r0.x * DD + c];
    }
    hcat[(size_t)n * DD + c] = bias[c] + (acc0 + acc1) * frcp(den0 + den1);
}

// ===== attention pass A: partial l per ksplit (no atomics, no memset) =====
__global__ __launch_bounds__(256) void k_attn_l(const unsigned short* __restrict__ Qb,
                                                const unsigned short* __restrict__ Kb,
                                                float* __restrict__ lpart) {
    const int tid = threadIdx.x;
    const int w = tid >> 6;
    const int lane = tid & 63;
    const int lq = lane & 15;
    const int g = lane >> 4;
    const int q0 = blockIdx.x * 64;
    const int ks = blockIdx.y;
    f32x4 zero = {0.f, 0.f, 0.f, 0.f};

    bf16x8 qf[4];
#pragma unroll
    for (int j = 0; j < 4; ++j)
        qf[j] = *(const bf16x8*)(Qb + ((size_t)w * N_NODES + q0 + j * 16 + lq) * NC + g * 8);
    const unsigned short* Kp = Kb + (size_t)w * N_NODES * NC;

    float l[4] = {0.f, 0.f, 0.f, 0.f};
    for (int kt = 0; kt < 16; ++kt) {
        const int k0 = ks * 1024 + kt * 64;
#pragma unroll
        for (int t = 0; t < 4; ++t) {
            const bf16x8 kf = *(const bf16x8*)(Kp + (size_t)(k0 + t * 16 + lq) * NC + g * 8);
#pragma unroll
            for (int j = 0; j < 4; ++j) {
                f32x4 st = __builtin_amdgcn_mfma_f32_16x16x32_bf16(kf, qf[j], zero, 0, 0, 0);
                l[j] += (fexp2(st[0]) + fexp2(st[1])) + (fexp2(st[2]) + fexp2(st[3]));
            }
        }
    }
#pragma unroll
    for (int j = 0; j < 4; ++j) {
        float lj = l[j];
        lj += __shfl_xor(lj, 16); lj += __shfl_xor(lj, 32);
        if (lane < 16)
            lpart[((size_t)ks * NH + w) * N_NODES + q0 + j * 16 + lq] = lj;
    }
}

// ===== attention pass B: head-merged PV, 32q/block, ksplit 8, 20480B LDS =====
__global__ __launch_bounds__(256, 2) void k_attn_pv(
        const unsigned short* __restrict__ Qb,
        const unsigned short* __restrict__ Kb,
        const unsigned short* __restrict__ Htb,
        const float* __restrict__ lpart,
        float* __restrict__ Opart) {
    __shared__ unsigned short htl[128 * 64];    // 16384 B, chunk-rotated
    __shared__ unsigned short plds[32 * 64];    // 4096 B, chunk-rotated
    const int tid = threadIdx.x;
    const int w = tid >> 6;
    const int lane = tid & 63;
    const int lq = lane & 15;
    const int g = lane >> 4;
    const int q0 = blockIdx.x * 32;
    const int ks = blockIdx.y;
    const int sd = tid >> 3, sc = tid & 7;
    f32x4 zero = {0.f, 0.f, 0.f, 0.f};

    float lg0[4], lg1[4];
    bf16x8 qreg0[4], qreg1[4];
#pragma unroll
    for (int h = 0; h < 4; ++h) {
        float s0 = 0.f, s1 = 0.f;
#pragma unroll
        for (int s = 0; s < 8; ++s) {
            s0 += lpart[((size_t)s * NH + h) * N_NODES + q0 + lq];
            s1 += lpart[((size_t)s * NH + h) * N_NODES + q0 + 16 + lq];
        }
        lg0[h] = -flog2(s0);
        lg1[h] = -flog2(s1);
        qreg0[h] = *(const bf16x8*)(Qb + ((size_t)h * N_NODES + q0 + lq) * NC + g * 8);
        qreg1[h] = *(const bf16x8*)(Qb + ((size_t)h * N_NODES + q0 + 16 + lq) * NC + g * 8);
    }

    f32x4 acc[2][2];
#pragma unroll
    for (int a = 0; a < 2; ++a) { acc[a][0] = zero; acc[a][1] = zero; }

    const int wch = 2 * w + (g >> 1);
    const int whalf = (g & 1) * 8;

    for (int kt = 0; kt < 16; ++kt) {
        const int k0 = ks * 1024 + kt * 64;
        __syncthreads();
#pragma unroll
        for (int mm = 0; mm < 4; ++mm) {
            int d = mm * 32 + sd;
            uint4 v = *(const uint4*)(Htb + (size_t)d * N_NODES + k0 + sc * 8);
            *(uint4*)&htl[d * 64 + ((sc + d) & 7) * 8] = v;
        }
        f32x4 ps0 = zero, ps1 = zero;
#pragma unroll
        for (int h = 0; h < 4; ++h) {
            const bf16x8 kf = *(const bf16x8*)(Kb + ((size_t)h * N_NODES + k0 + w * 16 + lq) * NC + g * 8);
            f32x4 st0 = __builtin_amdgcn_mfma_f32_16x16x32_bf16(kf, qreg0[h], zero, 0, 0, 0);
            f32x4 st1 = __builtin_amdgcn_mfma_f32_16x16x32_bf16(kf, qreg1[h], zero, 0, 0, 0);
#pragma unroll
            for (int r = 0; r < 4; ++r) {
                ps0[r] += fexp2(st0[r] + lg0[h]);
                ps1[r] += fexp2(st1[r] + lg1[h]);
            }
        }
        uint2 pk;
        pk.x = pk2bf(ps0[0], ps0[1]); pk.y = pk2bf(ps0[2], ps0[3]);
        {
            int row = lq;
            *(uint2*)((char*)plds + row * 128 + ((wch + row) & 7) * 16 + whalf) = pk;
        }
        pk.x = pk2bf(ps1[0], ps1[1]); pk.y = pk2bf(ps1[2], ps1[3]);
        {
            int row = 16 + lq;
            *(uint2*)((char*)plds + row * 128 + ((wch + row) & 7) * 16 + whalf) = pk;
        }
        __syncthreads();
#pragma unroll
        for (int kc = 0; kc < 2; ++kc) {
            int row0 = lq, row1 = 16 + lq;
            const bf16x8 af0 = *(const bf16x8*)((char*)plds + row0 * 128 + ((kc * 4 + g + row0) & 7) * 16);
            const bf16x8 af1 = *(const bf16x8*)((char*)plds + row1 * 128 + ((kc * 4 + g + row1) & 7) * 16);
#pragma unroll
            for (int dl = 0; dl < 2; ++dl) {
                int dd = (w * 2 + dl) * 16 + lq;
                const bf16x8 bf = *(const bf16x8*)&htl[dd * 64 + ((kc * 4 + g + dd) & 7) * 8];
                acc[dl][0] = __builtin_amdgcn_mfma_f32_16x16x32_bf16(af0, bf, acc[dl][0], 0, 0, 0);
                acc[dl][1] = __builtin_amdgcn_mfma_f32_16x16x32_bf16(af1, bf, acc[dl][1], 0, 0, 0);
            }
        }
    }
    const size_t ob = (size_t)ks * N_NODES + q0;
#pragma unroll
    for (int dl = 0; dl < 2; ++dl) {
        int d = (w * 2 + dl) * 16 + lq;
#pragma unroll
        for (int s = 0; s < 2; ++s)
#pragma unroll
            for (int r = 0; r < 4; ++r)
                Opart[(ob + s * 16 + 4 * g + r) * DD + d] = acc[dl][s][r];
    }
}

// ===== combine 8 splits, residual, LayerNorm =====
__global__ __launch_bounds__(128) void k_finalize(const float* __restrict__ Opart,
                                                  const float* __restrict__ hb,
                                                  const float* __restrict__ g,
                                                  const float* __restrict__ b,
                                                  float* __restrict__ out) {
    __shared__ float red[2];
    int n = blockIdx.x, c = threadIdx.x;
    const size_t ND = (size_t)N_NODES * DD;
    size_t idx = (size_t)n * DD + c;
    float y = hb[idx];
#pragma unroll
    for (int i = 0; i < 8; ++i) y += Opart[i * ND + idx];
    float s = y;
#pragma unroll
    for (int off = 1; off < 64; off <<= 1) s += __shfl_xor(s, off);
    if ((c & 63) == 0) red[c >> 6] = s;
    __syncthreads();
    float mu = (red[0] + red[1]) * (1.f / 128.f);
    float dv = y - mu;
    float vs = dv * dv;
#pragma unroll
    for (int off = 1; off < 64; off <<= 1) vs += __shfl_xor(vs, off);
    __syncthreads();
    if ((c & 63) == 0) red[c >> 6] = vs;
    __syncthreads();
    float rstd = rsqrtf((red[0] + red[1]) * (1.f / 128.f) + LN_EPS);
    out[idx] = dv * rstd * g[c] + b[c];
}

extern "C" void kernel_launch(void* const* d_in, const int* in_sizes, int n_in,
                              void* d_out, int out_size, void* d_ws, size_t ws_size,
                              hipStream_t stream) {
    const float* x        = (const float*)d_in[0];
    const int*   adj      = (const int*)d_in[1];
    const float* Wgat     = (const float*)d_in[2];
    const float* att_src  = (const float*)d_in[3];
    const float* att_dst  = (const float*)d_in[4];
    const float* bias_gat = (const float*)d_in[5];
    const float* Wq       = (const float*)d_in[6];
    const float* Wk       = (const float*)d_in[7];
    const float* Wpro     = (const float*)d_in[8];
    const float* ln_g     = (const float*)d_in[9];
    const float* ln_b     = (const float*)d_in[10];
    float* out = (float*)d_out;

    const size_t ND = (size_t)N_NODES * DD;
    unsigned short* Qb  = (unsigned short*)d_ws;          // 2 MB
    unsigned short* Kb  = Qb + (1 << 20);                 // 2 MB
    unsigned short* Htb = Kb + (1 << 20);                 // 2 MB
    unsigned short* Wgt = Htb + (1 << 20);                // 64 KB
    unsigned short* Wpt = Wgt + 32768;                    // 32 KB
    unsigned short* Wqt = Wpt + 16384;                    // 32 KB
    unsigned short* Wkt = Wqt + 16384;                    // 32 KB
    float* xw      = (float*)(Wkt + 16384);               // 4 MB
    float* hcat    = xw + ND;                             // 4 MB
    float* hbuf    = hcat + ND;                           // 4 MB
    float* asrc    = hbuf + ND;
    float* adst    = asrc + N_NODES * NH;
    float* lpart   = adst + N_NODES * NH;                 // 8 ks x 4 h x N = 1 MB
    int*   deg     = (int*)(lpart + 8 * NH * N_NODES);    // 32 KB (memset)
    int*   rowptr  = deg + 8192;
    int*   cursor  = rowptr + 8704;
    uint4* rec_csr = (uint4*)(cursor + 8704);             // ETOT*16B = 4.3 MB
    float* Opart   = (float*)(rec_csr + ETOT);            // 8 x [N,128] = 32 MB

    hipMemsetAsync(deg, 0, N_NODES * sizeof(int), stream);
    int cvtblocks = (ETOT + 255) / 256;
    k_cvt<<<cvtblocks, 256, 0, stream>>>(Wgat, Wpro, Wq, Wk, Wgt, Wpt, Wqt, Wkt, adj, deg);
    k_gemm_att<<<N_NODES / 32, 256, 0, stream>>>(x, Wgt, att_src, att_dst, xw, asrc, adst);
    k_scan<<<1, 1024, 0, stream>>>(deg, rowptr, cursor);
    int eblocks = (ETOT + 255) / 256;
    k_fill<<<eblocks, 256, 0, stream>>>(adj, asrc, adst, cursor, rec_csr);
    k_aggregate<<<N_NODES / 2, 256, 0, stream>>>(rowptr, rec_csr, xw, bias_gat, hcat);
    k_gemm_pro<<<N_NODES / 32, 256, 0, stream>>>(hcat, Wpt, Wqt, Wkt, hbuf, Htb, Qb, Kb);
    dim3 lgrid(N_NODES / 64, 8);
    k_attn_l<<<lgrid, 256, 0, stream>>>(Qb, Kb, lpart);
    dim3 agrid(N_NODES / 32, 8);
    k_attn_pv<<<agrid, 256, 0, stream>>>(Qb, Kb, Htb, lpart, Opart);
    k_finalize<<<N_NODES, 128, 0, stream>>>(Opart, hbuf, ln_g, ln_b, out);
}

// Round 15
// 257.461 us; speedup vs baseline: 1.0468x; 1.0468x over previous
//
#include <hip/hip_runtime.h>
#include <math.h>

#define N_NODES 8192
#define E_EDGES 262144
#define ETOT (E_EDGES + N_NODES)
#define F_IN 256
#define NH 4
#define NC 32
#define DD 128
#define NEG_SLOPE 0.2f
#define LN_EPS 1e-5f
// attention softmax in exp2 domain: fold log2(e)/sqrt(32) into Q at pack time
#define QK_SCALE (1.4426950408889634f / 5.656854249492381f)

typedef __attribute__((ext_vector_type(8))) short bf16x8;
typedef __attribute__((ext_vector_type(4))) float f32x4;

__device__ __forceinline__ float fexp2(float x) { return __builtin_amdgcn_exp2f(x); }
__device__ __forceinline__ float flog2(float x) { return __builtin_amdgcn_logf(x); }
__device__ __forceinline__ float frcp(float x)  { return __builtin_amdgcn_rcpf(x); }

__device__ __forceinline__ unsigned short f2bf(float f) {   // RTNE
    unsigned u = __float_as_uint(f);
    u += 0x7FFFu + ((u >> 16) & 1u);
    return (unsigned short)(u >> 16);
}
__device__ __forceinline__ unsigned pk2bf(float lo, float hi) {
    unsigned a = __float_as_uint(lo) + 0x8000u;
    unsigned b = __float_as_uint(hi) + 0x8000u;
    return __builtin_amdgcn_perm(b, a, 0x07060302u);
}

// ===== weight transpose/convert to bf16 + FUSED degree count =====
__global__ __launch_bounds__(256) void k_cvt(const float* __restrict__ Wgat,
                                             const float* __restrict__ Wpro,
                                             const float* __restrict__ Wq,
                                             const float* __restrict__ Wk,
                                             unsigned short* __restrict__ Wgt,
                                             unsigned short* __restrict__ Wpt,
                                             unsigned short* __restrict__ Wqt,
                                             unsigned short* __restrict__ Wkt,
                                             const int* __restrict__ adj,
                                             int* __restrict__ deg) {
    int t = blockIdx.x * 256 + threadIdx.x;
    if (t < 32768) {
        int c = t >> 8, k = t & 255;
        Wgt[t] = f2bf(Wgat[(size_t)k * 128 + c]);
    } else if (t < 49152) {
        int i = t - 32768, c = i >> 7, k = i & 127;
        Wpt[i] = f2bf(Wpro[(size_t)k * 128 + c]);
    } else if (t < 65536) {
        int i = t - 49152, h = i >> 12, r = i & 4095, c = r >> 7, k = r & 127;
        Wqt[i] = f2bf(Wq[h * 4096 + k * 32 + c]);
    } else if (t < 81920) {
        int i = t - 65536, h = i >> 12, r = i & 4095, c = r >> 7, k = r & 127;
        Wkt[i] = f2bf(Wk[h * 4096 + k * 32 + c]);
    }
    if (t < ETOT) {
        int d = (t < E_EDGES) ? adj[E_EDGES + t] : t - E_EDGES;
        atomicAdd(&deg[d], 1);
    }
}

// ===== MFMA GEMM xw = x @ Wgat, x converted to bf16 in staging, fused attcoef =====
__global__ __launch_bounds__(256) void k_gemm_att(const float* __restrict__ x,
                                                  const unsigned short* __restrict__ Wgt,
                                                  const float* __restrict__ att_src,
                                                  const float* __restrict__ att_dst,
                                                  float* __restrict__ xw,
                                                  float* __restrict__ asrc,
                                                  float* __restrict__ adst) {
    __shared__ unsigned short xs[32 * 256];   // chunk-rotated
    const int tid = threadIdx.x;
    const int w = tid >> 6, lane = tid & 63, lq = lane & 15, g = lane >> 4;
    const int n0 = blockIdx.x * 32;
#pragma unroll
    for (int m = 0; m < 4; ++m) {             // 1024 chunk-tasks
        int lin = m * 256 + tid;
        int row = lin >> 5, ch = lin & 31;
        const float* src = &x[(size_t)(n0 + row) * 256 + ch * 8];
        float4 v0 = *(const float4*)src;
        float4 v1 = *(const float4*)(src + 4);
        uint4 o;
        o.x = (unsigned)f2bf(v0.x) | ((unsigned)f2bf(v0.y) << 16);
        o.y = (unsigned)f2bf(v0.z) | ((unsigned)f2bf(v0.w) << 16);
        o.z = (unsigned)f2bf(v1.x) | ((unsigned)f2bf(v1.y) << 16);
        o.w = (unsigned)f2bf(v1.z) | ((unsigned)f2bf(v1.w) << 16);
        *(uint4*)&xs[row * 256 + ((ch + row) & 31) * 8] = o;
    }
    __syncthreads();
    f32x4 zero = {0.f, 0.f, 0.f, 0.f};
    f32x4 acc[2][2];
#pragma unroll
    for (int s = 0; s < 2; ++s) { acc[s][0] = zero; acc[s][1] = zero; }
#pragma unroll
    for (int kb = 0; kb < 8; ++kb) {
        bf16x8 af[2], bf[2];
#pragma unroll
        for (int s = 0; s < 2; ++s) {
            int row = s * 16 + lq;
            af[s] = *(const bf16x8*)&xs[row * 256 + (((kb * 4 + g) + row) & 31) * 8];
        }
#pragma unroll
        for (int c = 0; c < 2; ++c)
            bf[c] = *(const bf16x8*)(Wgt + (size_t)(w * 32 + c * 16 + lq) * 256 + kb * 32 + g * 8);
#pragma unroll
        for (int s = 0; s < 2; ++s)
#pragma unroll
            for (int c = 0; c < 2; ++c)
                acc[s][c] = __builtin_amdgcn_mfma_f32_16x16x32_bf16(af[s], bf[c], acc[s][c], 0, 0, 0);
    }
#pragma unroll
    for (int s = 0; s < 2; ++s)
#pragma unroll
        for (int c = 0; c < 2; ++c)
#pragma unroll
            for (int r = 0; r < 4; ++r)
                xw[(size_t)(n0 + s * 16 + 4 * g + r) * DD + w * 32 + c * 16 + lq] = acc[s][c][r];
    float avs0 = att_src[w * 32 + lq],      avd0 = att_dst[w * 32 + lq];
    float avs1 = att_src[w * 32 + 16 + lq], avd1 = att_dst[w * 32 + 16 + lq];
#pragma unroll
    for (int s = 0; s < 2; ++s) {
        f32x4 vs, vd;
#pragma unroll
        for (int r = 0; r < 4; ++r) {
            vs[r] = acc[s][0][r] * avs0 + acc[s][1][r] * avs1;
            vd[r] = acc[s][0][r] * avd0 + acc[s][1][r] * avd1;
        }
#pragma unroll
        for (int off = 1; off < 16; off <<= 1)
#pragma unroll
            for (int r = 0; r < 4; ++r) {
                vs[r] += __shfl_xor(vs[r], off);
                vd[r] += __shfl_xor(vd[r], off);
            }
        if (lq == 0) {
#pragma unroll
            for (int r = 0; r < 4; ++r) {
                asrc[(n0 + s * 16 + 4 * g + r) * 4 + w] = vs[r];
                adst[(n0 + s * 16 + 4 * g + r) * 4 + w] = vd[r];
            }
        }
    }
}

// ===== MFMA GEMM h = hcat @ Wpro + hbuf f32 + Htb transpose + MFMA q/k =====
__global__ __launch_bounds__(256) void k_gemm_pro(const float* __restrict__ hcat,
                                                  const unsigned short* __restrict__ Wpt,
                                                  const unsigned short* __restrict__ Wqt,
                                                  const unsigned short* __restrict__ Wkt,
                                                  float* __restrict__ hbuf,
                                                  unsigned short* __restrict__ Htb,
                                                  unsigned short* __restrict__ Qb,
                                                  unsigned short* __restrict__ Kb) {
    __shared__ unsigned short xs[32 * 128];
    __shared__ unsigned short hsd[32 * 128];
    const int tid = threadIdx.x;
    const int w = tid >> 6, lane = tid & 63, lq = lane & 15, g = lane >> 4;
    const int n0 = blockIdx.x * 32;
#pragma unroll
    for (int m = 0; m < 2; ++m) {
        int lin = m * 256 + tid;
        int row = lin >> 4, ch = lin & 15;
        const float* src = &hcat[(size_t)(n0 + row) * 128 + ch * 8];
        float4 v0 = *(const float4*)src;
        float4 v1 = *(const float4*)(src + 4);
        uint4 o;
        o.x = (unsigned)f2bf(v0.x) | ((unsigned)f2bf(v0.y) << 16);
        o.y = (unsigned)f2bf(v0.z) | ((unsigned)f2bf(v0.w) << 16);
        o.z = (unsigned)f2bf(v1.x) | ((unsigned)f2bf(v1.y) << 16);
        o.w = (unsigned)f2bf(v1.z) | ((unsigned)f2bf(v1.w) << 16);
        *(uint4*)&xs[row * 128 + ((ch + row) & 15) * 8] = o;
    }
    __syncthreads();
    f32x4 zero = {0.f, 0.f, 0.f, 0.f};
    f32x4 acc[2][2];
#pragma unroll
    for (int s = 0; s < 2; ++s) { acc[s][0] = zero; acc[s][1] = zero; }
#pragma unroll
    for (int kb = 0; kb < 4; ++kb) {
        bf16x8 af[2], bf[2];
#pragma unroll
        for (int s = 0; s < 2; ++s) {
            int row = s * 16 + lq;
            af[s] = *(const bf16x8*)&xs[row * 128 + (((kb * 4 + g) + row) & 15) * 8];
        }
#pragma unroll
        for (int c = 0; c < 2; ++c)
            bf[c] = *(const bf16x8*)(Wpt + (size_t)(w * 32 + c * 16 + lq) * 128 + kb * 32 + g * 8);
#pragma unroll
        for (int s = 0; s < 2; ++s)
#pragma unroll
            for (int c = 0; c < 2; ++c)
                acc[s][c] = __builtin_amdgcn_mfma_f32_16x16x32_bf16(af[s], bf[c], acc[s][c], 0, 0, 0);
    }
#pragma unroll
    for (int s = 0; s < 2; ++s)
#pragma unroll
        for (int c = 0; c < 2; ++c) {
            int col = w * 32 + c * 16 + lq;
#pragma unroll
            for (int r = 0; r < 4; ++r) {
                int row = s * 16 + 4 * g + r;
                hbuf[(size_t)(n0 + row) * 128 + col] = acc[s][c][r];
                hsd[row * 128 + (((col >> 3) + row) & 15) * 8 + (col & 7)] = f2bf(acc[s][c][r]);
            }
            uint2 hp;
            hp.x = pk2bf(acc[s][c][0], acc[s][c][1]);
            hp.y = pk2bf(acc[s][c][2], acc[s][c][3]);
            *(uint2*)(Htb + (size_t)col * N_NODES + n0 + s * 16 + 4 * g) = hp;
        }
    __syncthreads();
    f32x4 aq[2][2], ak[2][2];
#pragma unroll
    for (int s = 0; s < 2; ++s)
#pragma unroll
        for (int c = 0; c < 2; ++c) { aq[s][c] = zero; ak[s][c] = zero; }
#pragma unroll
    for (int kb = 0; kb < 4; ++kb) {
        bf16x8 af[2], bq[2], bk[2];
#pragma unroll
        for (int s = 0; s < 2; ++s) {
            int row = s * 16 + lq;
            af[s] = *(const bf16x8*)&hsd[row * 128 + (((kb * 4 + g) + row) & 15) * 8];
        }
#pragma unroll
        for (int c = 0; c < 2; ++c) {
            size_t widx = ((size_t)w * 32 + c * 16 + lq) * 128 + kb * 32 + g * 8;
            bq[c] = *(const bf16x8*)(Wqt + widx);
            bk[c] = *(const bf16x8*)(Wkt + widx);
        }
#pragma unroll
        for (int s = 0; s < 2; ++s)
#pragma unroll
            for (int c = 0; c < 2; ++c) {
                aq[s][c] = __builtin_amdgcn_mfma_f32_16x16x32_bf16(af[s], bq[c], aq[s][c], 0, 0, 0);
                ak[s][c] = __builtin_amdgcn_mfma_f32_16x16x32_bf16(af[s], bk[c], ak[s][c], 0, 0, 0);
            }
    }
#pragma unroll
    for (int s = 0; s < 2; ++s)
#pragma unroll
        for (int c = 0; c < 2; ++c)
#pragma unroll
            for (int r = 0; r < 4; ++r) {
                size_t nidx = (size_t)w * N_NODES + n0 + s * 16 + 4 * g + r;
                Qb[nidx * NC + c * 16 + lq] = f2bf(aq[s][c][r] * QK_SCALE);
                Kb[nidx * NC + c * 16 + lq] = f2bf(ak[s][c][r]);
            }
}

__device__ __forceinline__ void edge_sd(int e, const int* adj, int& s, int& d) {
    if (e < E_EDGES) { s = adj[e]; d = adj[E_EDGES + e]; }
    else { s = e - E_EDGES; d = s; }
}

// ===== single-block exclusive scan over deg[8192] -> rowptr, cursor =====
__global__ __launch_bounds__(1024) void k_scan(const int* __restrict__ deg,
                                               int* __restrict__ rowptr,
                                               int* __restrict__ cursor) {
    __shared__ int sm[1024];
    int t = threadIdx.x;
    int v[8], sum = 0;
#pragma unroll
    for (int j = 0; j < 8; ++j) { v[j] = deg[t * 8 + j]; sum += v[j]; }
    sm[t] = sum;
    __syncthreads();
    for (int off = 1; off < 1024; off <<= 1) {
        int x = (t >= off) ? sm[t - off] : 0;
        __syncthreads();
        sm[t] += x;
        __syncthreads();
    }
    int base = sm[t] - sum;
#pragma unroll
    for (int j = 0; j < 8; ++j) {
        rowptr[t * 8 + j] = base;
        cursor[t * 8 + j] = base;
        base += v[j];
    }
    if (t == 1023) rowptr[8192] = base;
}

// ===== fill CSR: ONE packed 16B record per edge {src, p01 bf16, p23 bf16, 0} =====
__global__ void k_fill(const int* __restrict__ adj, const float* __restrict__ asrc,
                       const float* __restrict__ adst, int* __restrict__ cursor,
                       uint4* __restrict__ rec_csr) {
    int e = blockIdx.x * blockDim.x + threadIdx.x;
    if (e >= ETOT) return;
    int s, d; edge_sd(e, adj, s, d);
    int pos = atomicAdd(&cursor[d], 1);
    float4 as4 = *(const float4*)&asrc[s * 4];
    float4 ad4 = *(const float4*)&adst[d * 4];
    const float L2E = 1.4426950408889634f;
    float v;
    float4 p;
    v = as4.x + ad4.x; v = v > 0.f ? v : NEG_SLOPE * v; p.x = fexp2(v * L2E);
    v = as4.y + ad4.y; v = v > 0.f ? v : NEG_SLOPE * v; p.y = fexp2(v * L2E);
    v = as4.z + ad4.z; v = v > 0.f ? v : NEG_SLOPE * v; p.z = fexp2(v * L2E);
    v = as4.w + ad4.w; v = v > 0.f ? v : NEG_SLOPE * v; p.w = fexp2(v * L2E);
    uint4 rec;
    rec.x = (unsigned)s;
    rec.y = pk2bf(p.x, p.y);
    rec.z = pk2bf(p.z, p.w);
    rec.w = 0u;
    rec_csr[pos] = rec;
}

__device__ __forceinline__ float rec_p(const uint4& r, int h) {
    unsigned w = (h < 2) ? r.y : r.z;
    return __uint_as_float((h & 1) ? (w & 0xFFFF0000u) : (w << 16));
}

// ===== per-node gather-aggregate: inline denominator, 4-wide unroll =====
__global__ __launch_bounds__(256) void k_aggregate(const int* __restrict__ rowptr,
                                                   const uint4* __restrict__ rec_csr,
                                                   const float* __restrict__ xw,
                                                   const float* __restrict__ bias,
                                                   float* __restrict__ hcat) {
    int n = blockIdx.x * 2 + (threadIdx.x >> 7);
    int c = threadIdx.x & 127;
    int h = c >> 5;
    int beg = rowptr[n], end = rowptr[n + 1];
    float acc0 = 0.f, acc1 = 0.f, den0 = 0.f, den1 = 0.f;
    int i = beg;
    for (; i + 4 <= end; i += 4) {
        uint4 r0 = rec_csr[i], r1 = rec_csr[i + 1];
        uint4 r2 = rec_csr[i + 2], r3 = rec_csr[i + 3];
        float p0 = rec_p(r0, h), p1 = rec_p(r1, h);
        float p2 = rec_p(r2, h), p3 = rec_p(r3, h);
        den0 += p0 + p1;
        den1 += p2 + p3;
        acc0 += p0 * xw[(size_t)r0.x * DD + c] + p1 * xw[(size_t)r1.x * DD + c];
        acc1 += p2 * xw[(size_t)r2.x * DD + c] + p3 * xw[(size_t)r3.x * DD + c];
    }
    for (; i < end; ++i) {
        uint4 r0 = rec_csr[i];
        float p0 = rec_p(r0, h);
        den0 += p0;
        acc0 += p0 * xw[(size_t)r0.x * DD + c];
    }
    hcat[(size_t)n * DD + c] = bias[c] + (acc0 + acc1) * frcp(den0 + den1);
}

// ===== attention pass A: l_h[n] = sum_m exp2(S) — 64q/block, ksplit 8, atomics =====
__global__ __launch_bounds__(256) void k_attn_l(const unsigned short* __restrict__ Qb,
                                                const unsigned short* __restrict__ Kb,
                                                float* __restrict__ lsum) {
    const int tid = threadIdx.x;
    const int w = tid >> 6;
    const int lane = tid & 63;
    const int lq = lane & 15;
    const int g = lane >> 4;
    const int q0 = blockIdx.x * 64;
    const int ks = blockIdx.y;
    f32x4 zero = {0.f, 0.f, 0.f, 0.f};

    bf16x8 qf[4];
#pragma unroll
    for (int j = 0; j < 4; ++j)
        qf[j] = *(const bf16x8*)(Qb + ((size_t)w * N_NODES + q0 + j * 16 + lq) * NC + g * 8);
    const unsigned short* Kp = Kb + (size_t)w * N_NODES * NC;

    float l[4] = {0.f, 0.f, 0.f, 0.f};
    for (int kt = 0; kt < 16; ++kt) {
        const int k0 = ks * 1024 + kt * 64;
#pragma unroll
        for (int t = 0; t < 4; ++t) {
            const bf16x8 kf = *(const bf16x8*)(Kp + (size_t)(k0 + t * 16 + lq) * NC + g * 8);
#pragma unroll
            for (int j = 0; j < 4; ++j) {
                f32x4 st = __builtin_amdgcn_mfma_f32_16x16x32_bf16(kf, qf[j], zero, 0, 0, 0);
                l[j] += (fexp2(st[0]) + fexp2(st[1])) + (fexp2(st[2]) + fexp2(st[3]));
            }
        }
    }
#pragma unroll
    for (int j = 0; j < 4; ++j) {
        float lj = l[j];
        lj += __shfl_xor(lj, 16); lj += __shfl_xor(lj, 32);
        if (lane < 16) atomicAdd(&lsum[w * N_NODES + q0 + j * 16 + lq], lj);
    }
}

// ===== attention pass B: head-merged PV, 32q/block, ksplit 8, 20480B LDS =====
__global__ __launch_bounds__(256, 2) void k_attn_pv(
        const unsigned short* __restrict__ Qb,
        const unsigned short* __restrict__ Kb,
        const unsigned short* __restrict__ Htb,
        const float* __restrict__ lsum,
        float* __restrict__ Opart) {
    __shared__ unsigned short htl[128 * 64];    // 16384 B, chunk-rotated
    __shared__ unsigned short plds[32 * 64];    // 4096 B, chunk-rotated
    const int tid = threadIdx.x;
    const int w = tid >> 6;
    const int lane = tid & 63;
    const int lq = lane & 15;
    const int g = lane >> 4;
    const int q0 = blockIdx.x * 32;
    const int ks = blockIdx.y;
    const int sd = tid >> 3, sc = tid & 7;
    f32x4 zero = {0.f, 0.f, 0.f, 0.f};

    float lg0[4], lg1[4];
    bf16x8 qreg0[4], qreg1[4];
#pragma unroll
    for (int h = 0; h < 4; ++h) {
        lg0[h] = -flog2(lsum[h * N_NODES + q0 + lq]);
        lg1[h] = -flog2(lsum[h * N_NODES + q0 + 16 + lq]);
        qreg0[h] = *(const bf16x8*)(Qb + ((size_t)h * N_NODES + q0 + lq) * NC + g * 8);
        qreg1[h] = *(const bf16x8*)(Qb + ((size_t)h * N_NODES + q0 + 16 + lq) * NC + g * 8);
    }

    f32x4 acc[2][2];
#pragma unroll
    for (int a = 0; a < 2; ++a) { acc[a][0] = zero; acc[a][1] = zero; }

    const int wch = 2 * w + (g >> 1);
    const int whalf = (g & 1) * 8;

    for (int kt = 0; kt < 16; ++kt) {
        const int k0 = ks * 1024 + kt * 64;
        __syncthreads();
#pragma unroll
        for (int mm = 0; mm < 4; ++mm) {
            int d = mm * 32 + sd;
            uint4 v = *(const uint4*)(Htb + (size_t)d * N_NODES + k0 + sc * 8);
            *(uint4*)&htl[d * 64 + ((sc + d) & 7) * 8] = v;
        }
        f32x4 ps0 = zero, ps1 = zero;
#pragma unroll
        for (int h = 0; h < 4; ++h) {
            const bf16x8 kf = *(const bf16x8*)(Kb + ((size_t)h * N_NODES + k0 + w * 16 + lq) * NC + g * 8);
            f32x4 st0 = __builtin_amdgcn_mfma_f32_16x16x32_bf16(kf, qreg0[h], zero, 0, 0, 0);
            f32x4 st1 = __builtin_amdgcn_mfma_f32_16x16x32_bf16(kf, qreg1[h], zero, 0, 0, 0);
#pragma unroll
            for (int r = 0; r < 4; ++r) {
                ps0[r] += fexp2(st0[r] + lg0[h]);
                ps1[r] += fexp2(st1[r] + lg1[h]);
            }
        }
        uint2 pk;
        pk.x = pk2bf(ps0[0], ps0[1]); pk.y = pk2bf(ps0[2], ps0[3]);
        {
            int row = lq;
            *(uint2*)((char*)plds + row * 128 + ((wch + row) & 7) * 16 + whalf) = pk;
        }
        pk.x = pk2bf(ps1[0], ps1[1]); pk.y = pk2bf(ps1[2], ps1[3]);
        {
            int row = 16 + lq;
            *(uint2*)((char*)plds + row * 128 + ((wch + row) & 7) * 16 + whalf) = pk;
        }
        __syncthreads();
#pragma unroll
        for (int kc = 0; kc < 2; ++kc) {
            int row0 = lq, row1 = 16 + lq;
            const bf16x8 af0 = *(const bf16x8*)((char*)plds + row0 * 128 + ((kc * 4 + g + row0) & 7) * 16);
            const bf16x8 af1 = *(const bf16x8*)((char*)plds + row1 * 128 + ((kc * 4 + g + row1) & 7) * 16);
#pragma unroll
            for (int dl = 0; dl < 2; ++dl) {
                int dd = (w * 2 + dl) * 16 + lq;
                const bf16x8 bf = *(const bf16x8*)&htl[dd * 64 + ((kc * 4 + g + dd) & 7) * 8];
                acc[dl][0] = __builtin_amdgcn_mfma_f32_16x16x32_bf16(af0, bf, acc[dl][0], 0, 0, 0);
                acc[dl][1] = __builtin_amdgcn_mfma_f32_16x16x32_bf16(af1, bf, acc[dl][1], 0, 0, 0);
            }
        }
    }
    const size_t ob = (size_t)ks * N_NODES + q0;
#pragma unroll
    for (int dl = 0; dl < 2; ++dl) {
        int d = (w * 2 + dl) * 16 + lq;
#pragma unroll
        for (int s = 0; s < 2; ++s)
#pragma unroll
            for (int r = 0; r < 4; ++r)
                Opart[(ob + s * 16 + 4 * g + r) * DD + d] = acc[dl][s][r];
    }
}

// ===== combine 8 splits, residual, LayerNorm =====
__global__ __launch_bounds__(128) void k_finalize(const float* __restrict__ Opart,
                                                  const float* __restrict__ hb,
                                                  const float* __restrict__ g,
                                                  const float* __restrict__ b,
                                                  float* __restrict__ out) {
    __shared__ float red[2];
    int n = blockIdx.x, c = threadIdx.x;
    const size_t ND = (size_t)N_NODES * DD;
    size_t idx = (size_t)n * DD + c;
    float y = hb[idx];
#pragma unroll
    for (int i = 0; i < 8; ++i) y += Opart[i * ND + idx];
    float s = y;
#pragma unroll
    for (int off = 1; off < 64; off <<= 1) s += __shfl_xor(s, off);
    if ((c & 63) == 0) red[c >> 6] = s;
    __syncthreads();
    float mu = (red[0] + red[1]) * (1.f / 128.f);
    float dv = y - mu;
    float vs = dv * dv;
#pragma unroll
    for (int off = 1; off < 64; off <<= 1) vs += __shfl_xor(vs, off);
    __syncthreads();
    if ((c & 63) == 0) red[c >> 6] = vs;
    __syncthreads();
    float rstd = rsqrtf((red[0] + red[1]) * (1.f / 128.f) + LN_EPS);
    out[idx] = dv * rstd * g[c] + b[c];
}

extern "C" void kernel_launch(void* const* d_in, const int* in_sizes, int n_in,
                              void* d_out, int out_size, void* d_ws, size_t ws_size,
                              hipStream_t stream) {
    const float* x        = (const float*)d_in[0];
    const int*   adj      = (const int*)d_in[1];
    const float* Wgat     = (const float*)d_in[2];
    const float* att_src  = (const float*)d_in[3];
    const float* att_dst  = (const float*)d_in[4];
    const float* bias_gat = (const float*)d_in[5];
    const float* Wq       = (const float*)d_in[6];
    const float* Wk       = (const float*)d_in[7];
    const float* Wpro     = (const float*)d_in[8];
    const float* ln_g     = (const float*)d_in[9];
    const float* ln_b     = (const float*)d_in[10];
    float* out = (float*)d_out;

    const size_t ND = (size_t)N_NODES * DD;
    unsigned short* Qb  = (unsigned short*)d_ws;          // 2 MB
    unsigned short* Kb  = Qb + (1 << 20);                 // 2 MB
    unsigned short* Htb = Kb + (1 << 20);                 // 2 MB
    unsigned short* Wgt = Htb + (1 << 20);                // 64 KB
    unsigned short* Wpt = Wgt + 32768;                    // 32 KB
    unsigned short* Wqt = Wpt + 16384;                    // 32 KB
    unsigned short* Wkt = Wqt + 16384;                    // 32 KB
    float* xw      = (float*)(Wkt + 16384);               // 4 MB
    float* hcat    = xw + ND;                             // 4 MB
    float* hbuf    = hcat + ND;                           // 4 MB
    float* asrc    = hbuf + ND;
    float* adst    = asrc + N_NODES * NH;
    float* lsum    = adst + N_NODES * NH;                 // 128 KB (memset w/ deg)
    int*   deg     = (int*)(lsum + N_NODES * NH);         // 32 KB
    int*   rowptr  = deg + 8192;
    int*   cursor  = rowptr + 8704;
    uint4* rec_csr = (uint4*)(cursor + 8704);             // ETOT*16B = 4.3 MB
    float* Opart   = (float*)(rec_csr + ETOT);            // 8 x [N,128] = 32 MB

    hipMemsetAsync(lsum, 0, N_NODES * NH * sizeof(float) + N_NODES * sizeof(int), stream);
    int cvtblocks = (ETOT + 255) / 256;
    k_cvt<<<cvtblocks, 256, 0, stream>>>(Wgat, Wpro, Wq, Wk, Wgt, Wpt, Wqt, Wkt, adj, deg);
    k_gemm_att<<<N_NODES / 32, 256, 0, stream>>>(x, Wgt, att_src, att_dst, xw, asrc, adst);
    k_scan<<<1, 1024, 0, stream>>>(deg, rowptr, cursor);
    int eblocks = (ETOT + 255) / 256;
    k_fill<<<eblocks, 256, 0, stream>>>(adj, asrc, adst, cursor, rec_csr);
    k_aggregate<<<N_NODES / 2, 256, 0, stream>>>(rowptr, rec_csr, xw, bias_gat, hcat);
    k_gemm_pro<<<N_NODES / 32, 256, 0, stream>>>(hcat, Wpt, Wqt, Wkt, hbuf, Htb, Qb, Kb);
    dim3 lgrid(N_NODES / 64, 8);
    k_attn_l<<<lgrid, 256, 0, stream>>>(Qb, Kb, lsum);
    dim3 agrid(N_NODES / 32, 8);
    k_attn_pv<<<agrid, 256, 0, stream>>>(Qb, Kb, Htb, lsum, Opart);
    k_finalize<<<N_NODES, 128, 0, stream>>>(Opart, hbuf, ln_g, ln_b, out);
}